// Round 1
// baseline (120.639 us; speedup 1.0000x reference)
//
#include <hip/hip_runtime.h>
#include <cfloat>

// ---------------------------------------------------------------------------
// Kernel A: segment boundaries via binary search over the SORTED edge_batch.
// seg[g] = first index i with edge_batch[i] >= g, for g in [0, G]. seg[G] = E.
// ---------------------------------------------------------------------------
__global__ __launch_bounds__(256) void seg_bounds_kernel(
    const int* __restrict__ eb, int E, int G, int* __restrict__ seg)
{
    int g = blockIdx.x * blockDim.x + threadIdx.x;
    if (g > G) return;
    int lo = 0, hi = E;
    while (lo < hi) {
        int mid = (lo + hi) >> 1;   // ~21 iterations; edge_batch is L2/L3-hot
        if (eb[mid] < g) lo = mid + 1; else hi = mid;
    }
    seg[g] = lo;
}

// ---------------------------------------------------------------------------
// Kernel B: one block per graph. 256 threads = 16 row-slots x 16 float4 cols.
// Single pass over the graph's contiguous edge rows: sum / sumsq / max / min.
// var = sumsq/count - mean^2 (clamped >= 0). Empty segments -> all zeros,
// matching the reference's maximum(counts,1) + where(nonempty, ...) semantics.
// Output row layout (float4 units, 160 per row):
//   [0:32)=metadata  [32:48)=mean  [48:64)=var  [64:80)=max  [80:96)=min
//   [96:128)=attended  [128:160)=current
// ---------------------------------------------------------------------------
__global__ __launch_bounds__(256) void graph_embed_kernel(
    const float4* __restrict__ edges,  // E x 16 float4
    const float4* __restrict__ meta,   // G x 32 float4
    const float4* __restrict__ att,    // G x 32 float4
    const float4* __restrict__ cur,    // G x 32 float4
    const int*    __restrict__ seg,    // G+1
    float4*       __restrict__ out)    // G x 160 float4
{
    const int g   = blockIdx.x;
    const int tid = threadIdx.x;
    const int f   = tid & 15;   // float4 column within a 64-float row
    const int r   = tid >> 4;   // row slot 0..15

    // Passthrough copies first — their VMEM traffic overlaps the edge scan.
    {
        const size_t ob = (size_t)g * 160;
        const size_t ib = (size_t)g * 32;
        if (tid < 32)      out[ob +        tid      ] = meta[ib + tid];
        else if (tid < 64) out[ob +  96 + (tid - 32)] = att [ib + (tid - 32)];
        else if (tid < 96) out[ob + 128 + (tid - 64)] = cur [ib + (tid - 64)];
    }

    const int start = seg[g];
    const int end   = seg[g + 1];
    const int count = end - start;

    float4 sum = make_float4(0.f, 0.f, 0.f, 0.f);
    float4 sq  = make_float4(0.f, 0.f, 0.f, 0.f);
    float4 mx  = make_float4(-FLT_MAX, -FLT_MAX, -FLT_MAX, -FLT_MAX);
    float4 mn  = make_float4( FLT_MAX,  FLT_MAX,  FLT_MAX,  FLT_MAX);

    for (int row = start + r; row < end; row += 16) {
        float4 v = edges[(size_t)row * 16 + f];   // 16B/lane, fully coalesced
        sum.x += v.x;       sum.y += v.y;       sum.z += v.z;       sum.w += v.w;
        sq.x  += v.x * v.x; sq.y  += v.y * v.y; sq.z  += v.z * v.z; sq.w  += v.w * v.w;
        mx.x = fmaxf(mx.x, v.x); mx.y = fmaxf(mx.y, v.y);
        mx.z = fmaxf(mx.z, v.z); mx.w = fmaxf(mx.w, v.w);
        mn.x = fminf(mn.x, v.x); mn.y = fminf(mn.y, v.y);
        mn.z = fminf(mn.z, v.z); mn.w = fminf(mn.w, v.w);
    }

    __shared__ float4 s_sum[16][16];
    __shared__ float4 s_sq [16][16];
    __shared__ float4 s_mx [16][16];
    __shared__ float4 s_mn [16][16];
    s_sum[r][f] = sum; s_sq[r][f] = sq; s_mx[r][f] = mx; s_mn[r][f] = mn;
    __syncthreads();

    #pragma unroll
    for (int step = 8; step >= 1; step >>= 1) {
        if (r < step) {
            float4 a = s_sum[r][f], b = s_sum[r + step][f];
            a.x += b.x; a.y += b.y; a.z += b.z; a.w += b.w;
            s_sum[r][f] = a;
            float4 c = s_sq[r][f], d = s_sq[r + step][f];
            c.x += d.x; c.y += d.y; c.z += d.z; c.w += d.w;
            s_sq[r][f] = c;
            float4 e = s_mx[r][f], h = s_mx[r + step][f];
            e.x = fmaxf(e.x, h.x); e.y = fmaxf(e.y, h.y);
            e.z = fmaxf(e.z, h.z); e.w = fmaxf(e.w, h.w);
            s_mx[r][f] = e;
            float4 p = s_mn[r][f], q = s_mn[r + step][f];
            p.x = fminf(p.x, q.x); p.y = fminf(p.y, q.y);
            p.z = fminf(p.z, q.z); p.w = fminf(p.w, q.w);
            s_mn[r][f] = p;
        }
        __syncthreads();
    }

    if (tid < 16) {
        float4 S = s_sum[0][tid], Q = s_sq[0][tid];
        float4 X = s_mx[0][tid],  N = s_mn[0][tid];
        float4 mean, var;
        if (count > 0) {
            const float inv = 1.0f / (float)count;
            mean.x = S.x * inv; mean.y = S.y * inv;
            mean.z = S.z * inv; mean.w = S.w * inv;
            var.x = fmaxf(Q.x * inv - mean.x * mean.x, 0.f);
            var.y = fmaxf(Q.y * inv - mean.y * mean.y, 0.f);
            var.z = fmaxf(Q.z * inv - mean.z * mean.z, 0.f);
            var.w = fmaxf(Q.w * inv - mean.w * mean.w, 0.f);
        } else {
            mean = make_float4(0.f, 0.f, 0.f, 0.f);
            var = mean; X = mean; N = mean;
        }
        float4* orow = out + (size_t)g * 160;
        orow[32 + tid] = mean;
        orow[48 + tid] = var;
        orow[64 + tid] = X;
        orow[80 + tid] = N;
    }
}

extern "C" void kernel_launch(void* const* d_in, const int* in_sizes, int n_in,
                              void* d_out, int out_size, void* d_ws, size_t ws_size,
                              hipStream_t stream)
{
    const float* h_edges = (const float*)d_in[0];
    const float* h_meta  = (const float*)d_in[1];
    const float* h_att   = (const float*)d_in[2];
    const float* h_cur   = (const float*)d_in[3];
    const int*   e_batch = (const int*)d_in[4];

    const int E = in_sizes[4];          // 2,000,000
    const int G = in_sizes[1] / 128;    // 8192

    int* seg = (int*)d_ws;              // (G+1) ints = 32,772 B of scratch

    seg_bounds_kernel<<<(G + 1 + 255) / 256, 256, 0, stream>>>(e_batch, E, G, seg);

    graph_embed_kernel<<<G, 256, 0, stream>>>(
        (const float4*)h_edges, (const float4*)h_meta, (const float4*)h_att,
        (const float4*)h_cur, seg, (float4*)d_out);
}

// Round 2
// 119.356 us; speedup vs baseline: 1.0107x; 1.0107x over previous
//
#include <hip/hip_runtime.h>
#include <cfloat>

// ---------------------------------------------------------------------------
// Kernel A: segment boundaries via binary search over the SORTED edge_batch.
// seg[g] = first index i with edge_batch[i] >= g, for g in [0, G]. seg[G] = E.
// ---------------------------------------------------------------------------
__global__ __launch_bounds__(256) void seg_bounds_kernel(
    const int* __restrict__ eb, int E, int G, int* __restrict__ seg)
{
    int g = blockIdx.x * blockDim.x + threadIdx.x;
    if (g > G) return;
    int lo = 0, hi = E;
    while (lo < hi) {
        int mid = (lo + hi) >> 1;   // ~21 iterations; edge_batch is L2/L3-hot
        if (eb[mid] < g) lo = mid + 1; else hi = mid;
    }
    seg[g] = lo;
}

// ---------------------------------------------------------------------------
// Kernel B: one block per graph. 256 threads = 16 row-slots x 16 float4 cols.
// Single pass over the graph's contiguous edge rows: sum / sumsq / max / min.
// Row loop unrolled 4x: 4 independent dwordx4 loads in flight per thread
// (4 KB/wave outstanding -> 128 KB/CU at 32 waves, above the ~22 KB
// latency-BW product at 900cy HBM latency). var = sumsq/count - mean^2.
// Empty segments -> all zeros (matches reference maximum(counts,1)+where).
// Output row layout (float4 units, 160 per row):
//   [0:32)=metadata  [32:48)=mean  [48:64)=var  [64:80)=max  [80:96)=min
//   [96:128)=attended  [128:160)=current
// ---------------------------------------------------------------------------
#define ACC(v)                                                            \
    do {                                                                  \
        sum.x += (v).x; sum.y += (v).y; sum.z += (v).z; sum.w += (v).w;   \
        sq.x += (v).x * (v).x; sq.y += (v).y * (v).y;                     \
        sq.z += (v).z * (v).z; sq.w += (v).w * (v).w;                     \
        mx.x = fmaxf(mx.x, (v).x); mx.y = fmaxf(mx.y, (v).y);             \
        mx.z = fmaxf(mx.z, (v).z); mx.w = fmaxf(mx.w, (v).w);             \
        mn.x = fminf(mn.x, (v).x); mn.y = fminf(mn.y, (v).y);             \
        mn.z = fminf(mn.z, (v).z); mn.w = fminf(mn.w, (v).w);             \
    } while (0)

__global__ __launch_bounds__(256) void graph_embed_kernel(
    const float4* __restrict__ edges,  // E x 16 float4
    const float4* __restrict__ meta,   // G x 32 float4
    const float4* __restrict__ att,    // G x 32 float4
    const float4* __restrict__ cur,    // G x 32 float4
    const int*    __restrict__ seg,    // G+1
    float4*       __restrict__ out)    // G x 160 float4
{
    const int g   = blockIdx.x;
    const int tid = threadIdx.x;
    const int f   = tid & 15;   // float4 column within a 64-float row
    const int r   = tid >> 4;   // row slot 0..15

    // Passthrough copies first — their VMEM traffic overlaps the edge scan.
    {
        const size_t ob = (size_t)g * 160;
        const size_t ib = (size_t)g * 32;
        if (tid < 32)      out[ob +        tid      ] = meta[ib + tid];
        else if (tid < 64) out[ob +  96 + (tid - 32)] = att [ib + (tid - 32)];
        else if (tid < 96) out[ob + 128 + (tid - 64)] = cur [ib + (tid - 64)];
    }

    const int start = seg[g];
    const int end   = seg[g + 1];
    const int count = end - start;

    float4 sum = make_float4(0.f, 0.f, 0.f, 0.f);
    float4 sq  = make_float4(0.f, 0.f, 0.f, 0.f);
    float4 mx  = make_float4(-FLT_MAX, -FLT_MAX, -FLT_MAX, -FLT_MAX);
    float4 mn  = make_float4( FLT_MAX,  FLT_MAX,  FLT_MAX,  FLT_MAX);

    int row = start + r;
    // Main loop: 4 rows per trip (stride 16 each) -> 4 loads in flight.
    for (; row + 48 < end; row += 64) {
        float4 v0 = edges[(size_t)(row     ) * 16 + f];
        float4 v1 = edges[(size_t)(row + 16) * 16 + f];
        float4 v2 = edges[(size_t)(row + 32) * 16 + f];
        float4 v3 = edges[(size_t)(row + 48) * 16 + f];
        ACC(v0); ACC(v1); ACC(v2); ACC(v3);
    }
    // Remainder (< 4 trips).
    for (; row < end; row += 16) {
        float4 v = edges[(size_t)row * 16 + f];
        ACC(v);
    }

    __shared__ float4 s_sum[16][16];
    __shared__ float4 s_sq [16][16];
    __shared__ float4 s_mx [16][16];
    __shared__ float4 s_mn [16][16];
    s_sum[r][f] = sum; s_sq[r][f] = sq; s_mx[r][f] = mx; s_mn[r][f] = mn;
    __syncthreads();

    #pragma unroll
    for (int step = 8; step >= 1; step >>= 1) {
        if (r < step) {
            float4 a = s_sum[r][f], b = s_sum[r + step][f];
            a.x += b.x; a.y += b.y; a.z += b.z; a.w += b.w;
            s_sum[r][f] = a;
            float4 c = s_sq[r][f], d = s_sq[r + step][f];
            c.x += d.x; c.y += d.y; c.z += d.z; c.w += d.w;
            s_sq[r][f] = c;
            float4 e = s_mx[r][f], h = s_mx[r + step][f];
            e.x = fmaxf(e.x, h.x); e.y = fmaxf(e.y, h.y);
            e.z = fmaxf(e.z, h.z); e.w = fmaxf(e.w, h.w);
            s_mx[r][f] = e;
            float4 p = s_mn[r][f], q = s_mn[r + step][f];
            p.x = fminf(p.x, q.x); p.y = fminf(p.y, q.y);
            p.z = fminf(p.z, q.z); p.w = fminf(p.w, q.w);
            s_mn[r][f] = p;
        }
        __syncthreads();
    }

    if (tid < 16) {
        float4 S = s_sum[0][tid], Q = s_sq[0][tid];
        float4 X = s_mx[0][tid],  N = s_mn[0][tid];
        float4 mean, var;
        if (count > 0) {
            const float inv = 1.0f / (float)count;
            mean.x = S.x * inv; mean.y = S.y * inv;
            mean.z = S.z * inv; mean.w = S.w * inv;
            var.x = fmaxf(Q.x * inv - mean.x * mean.x, 0.f);
            var.y = fmaxf(Q.y * inv - mean.y * mean.y, 0.f);
            var.z = fmaxf(Q.z * inv - mean.z * mean.z, 0.f);
            var.w = fmaxf(Q.w * inv - mean.w * mean.w, 0.f);
        } else {
            mean = make_float4(0.f, 0.f, 0.f, 0.f);
            var = mean; X = mean; N = mean;
        }
        float4* orow = out + (size_t)g * 160;
        orow[32 + tid] = mean;
        orow[48 + tid] = var;
        orow[64 + tid] = X;
        orow[80 + tid] = N;
    }
}

extern "C" void kernel_launch(void* const* d_in, const int* in_sizes, int n_in,
                              void* d_out, int out_size, void* d_ws, size_t ws_size,
                              hipStream_t stream)
{
    const float* h_edges = (const float*)d_in[0];
    const float* h_meta  = (const float*)d_in[1];
    const float* h_att   = (const float*)d_in[2];
    const float* h_cur   = (const float*)d_in[3];
    const int*   e_batch = (const int*)d_in[4];

    const int E = in_sizes[4];          // 2,000,000
    const int G = in_sizes[1] / 128;    // 8192

    int* seg = (int*)d_ws;              // (G+1) ints = 32,772 B of scratch

    seg_bounds_kernel<<<(G + 1 + 255) / 256, 256, 0, stream>>>(e_batch, E, G, seg);

    graph_embed_kernel<<<G, 256, 0, stream>>>(
        (const float4*)h_edges, (const float4*)h_meta, (const float4*)h_att,
        (const float4*)h_cur, seg, (float4*)d_out);
}